// Round 13
// baseline (400.230 us; speedup 1.0000x reference)
//
#include <hip/hip_runtime.h>

// D2Q9 LBM single step; LDS exchange; per-CELL collide; CROSS-TILE PIPELINE.
// Layouts: f[x][y][9], rho[x][y], u[x][y][2], mask[x][y], out[x][y][12].
//
// R3: global gather txn-bound (179us). R5: LDS exchange, VALU-bound (146us).
// R6: algebra hoist (128us). R12: per-cell indexing -> VALU 22%, but 121us
// with nothing saturated => latency/barrier-bound. This round: each block
// walks 4 x-tiles, prefetching tile t+1's globals during tile t (hides HBM
// latency); staging is wave-local (wave w == output row w) so the
// stage->store barrier vanishes: 3 barriers/tile, stores overlap next A.
//
// fstar layout per halo row (stride 608): [0..575] interior cells (hc-1)*9,
// [576..584] left halo cell, [585..593] right halo cell.
// stage: wave-local, cell c of wave w at (64*w + c)*13, 12 payload words.

#define NX 2048
#define NY 2048
#define WRAP 2047
#define TR 8
#define TC 64
#define NT 512
#define TILES 4
#define RS 608
#define FSTARW 6080     // 10 * 608
#define STAGEW 6656     // 512 * 13

typedef float floatx4 __attribute__((ext_vector_type(4)));

#define LOADT(tt, ss) do {                                                     \
    const int xadd_ = (tt) * TR;                                               \
    _Pragma("unroll")                                                          \
    for (int it_ = 0; it_ < 3; ++it_) if (bvalid[it_]) {                       \
        const int xr_ = (brow[it_] + xadd_) & WRAP;                            \
        bv[ss][it_] = *reinterpret_cast<const floatx4*>(f + xr_ * 18432 + bgcol[it_]); } \
    if (eval_) { const int xr_ = (erow + xadd_) & WRAP;                        \
        ev[ss] = f[xr_ * 18432 + egcol]; }                                     \
    _Pragma("unroll")                                                          \
    for (int it_ = 0; it_ < 2; ++it_) if (cvalid[it_]) {                       \
        const int xr_ = (crow[it_] + xadd_) & WRAP;                            \
        const int g_ = xr_ * NY + cgcol[it_];                                  \
        rr[ss][it_] = rho[g_]; uu[ss][it_] = u2[g_]; }                         \
    { const int xr_ = (mrow + xadd_) & WRAP;                                   \
      mk[ss] = mask[xr_ * NY + y0 + c]; }                                      \
} while (0)

__global__ __launch_bounds__(NT, 6) void lbm_step_kernel(
    const float* __restrict__ f,
    const float* __restrict__ rho,
    const float* __restrict__ u,
    const int*   __restrict__ mask,
    float*       __restrict__ out)
{
    __shared__ __align__(16) float fstar[FSTARW];
    __shared__ __align__(16) float stg[STAGEW];

    const int tid = threadIdx.x;
    const int y0 = blockIdx.x * TC;
    const int xbase = blockIdx.y * (TR * TILES);

    const float2* __restrict__ u2 = reinterpret_cast<const float2*>(u);

    // ---- per-thread invariant indexing (computed once, reused 4 tiles) ----
    int brow[3], bldst[3], bgcol[3]; bool bvalid[3];
    #pragma unroll
    for (int it = 0; it < 3; ++it) {
        const int k4 = tid + it * NT;
        bvalid[it] = (k4 < 1440);                 // 10 rows x 144 float4
        const int row = (unsigned)k4 / 144u;
        const int col4 = k4 - row * 144;
        brow[it]  = xbase - 1 + row;
        bldst[it] = row * RS + col4 * 4;
        bgcol[it] = y0 * 9 + col4 * 4;
    }
    const bool eval_ = (tid < 180);               // 2 halo cols x 10 rows x 9
    int erow = 0, edst = 0, egcol = 0;
    if (eval_) {
        const int side = tid >= 90;
        const int er   = side ? tid - 90 : tid;
        const int rowE = (unsigned)er / 9u;
        const int iE   = er - rowE * 9;
        erow  = xbase - 1 + rowE;
        edst  = rowE * RS + (side ? 585 : 576) + iE;
        const int yc = side ? ((y0 + TC) & WRAP) : ((y0 - 1) & WRAP);
        egcol = yc * 9 + iE;
    }
    int crow[2], cbase[2], cgcol[2]; bool cvalid[2];
    #pragma unroll
    for (int it = 0; it < 2; ++it) {
        const int k = tid + it * NT;
        cvalid[it] = (k < 660);                   // 10 x 66 halo cells
        const int hr = (unsigned)k / 66u;
        const int hc = k - hr * 66;
        crow[it]  = xbase - 1 + hr;
        cbase[it] = hr * RS + (hc == 0 ? 576 : (hc == 65 ? 585 : (hc - 1) * 9));
        cgcol[it] = (y0 - 1 + hc) & WRAP;
    }
    const int w = tid >> 6;                       // wave id == tile row
    const int c = tid & 63;
    const int mrow = xbase + w;
    const int colmid = c * 9;
    const int colL = (c == 0)  ? 576 : (c - 1) * 9;
    const int colR = (c == 63) ? 585 : (c + 1) * 9;
    const int rA = w * RS, rB2 = rA + RS, rC2 = rB2 + RS;
    const int sbase = tid * 13;                   // == w*832 + c*13 (wave-local)
    int lread[3], ocol[3];
    #pragma unroll
    for (int it = 0; it < 3; ++it) {
        const int k4w = c + it * 64;              // wave-local float4 index, 0..191
        const int cc = (unsigned)k4w / 3u;
        const int q  = k4w - cc * 3;
        lread[it] = w * 832 + cc * 13 + q * 4;
        ocol[it]  = y0 * 12 + k4w * 4;
    }

    const float ITAU = 1.0f / 0.6f;
    const float OMT  = 1.0f - ITAU;

    floatx4 bv[2][3]; float ev[2]; float rr[2][2]; float2 uu[2][2]; int mk[2];

    LOADT(0, 0);

    #pragma unroll
    for (int t = 0; t < TILES; ++t) {
        const int s = t & 1;

        // ---- A: raw f tile -> fstar ----
        #pragma unroll
        for (int it = 0; it < 3; ++it)
            if (bvalid[it]) *reinterpret_cast<floatx4*>(&fstar[bldst[it]]) = bv[s][it];
        if (eval_) fstar[edst] = ev[s];

        if (t + 1 < TILES) {                      // prefetch next tile's globals
            if (s == 0) LOADT(t + 1, 1); else LOADT(t + 1, 0);
        }
        __syncthreads();                          // (1) fstar visible

        // ---- B: collide per cell, in place ----
        #pragma unroll
        for (int it = 0; it < 2; ++it) if (cvalid[it]) {
            const int b0 = cbase[it];
            float fi[9];
            #pragma unroll
            for (int i = 0; i < 9; ++i) fi[i] = fstar[b0 + i];
            const float rn = rr[s][it];
            const float ux = uu[s][it].x, uy = uu[s][it].y;
            const float C  = 1.0f - 1.5f * (ux * ux + uy * uy);
            const float a  = 3.0f * ux, b = 3.0f * uy;
            const float p  = a + b, q = a - b;
            const float ha = 0.5f * a * a, hb = 0.5f * b * b;
            const float hp = 0.5f * p * p, hq = 0.5f * q * q;
            const float Pm = rn * (4.0f / 9.0f);
            const float Ps = rn * (1.0f / 9.0f);
            const float Pd = rn * (1.0f / 36.0f);
            float feq[9];
            feq[0] = Pm * C;
            feq[1] = Ps * (C + a + ha);
            feq[2] = Ps * (C + b + hb);
            feq[3] = Ps * (C - a + ha);
            feq[4] = Ps * (C - b + hb);
            feq[5] = Pd * (C + p + hp);
            feq[6] = Pd * (C - q + hq);
            feq[7] = Pd * (C - p + hp);
            feq[8] = Pd * (C + q + hq);
            #pragma unroll
            for (int i = 0; i < 9; ++i)
                fstar[b0 + i] = fmaf(feq[i], ITAU, OMT * fi[i]);
        }
        __syncthreads();                          // (2) f* visible

        // ---- C: stream-gather + bounce-back ----
        float fn[9];
        fn[0] = fstar[rB2 + colmid + 0];
        fn[1] = fstar[rA  + colmid + 1];
        fn[2] = fstar[rB2 + colL   + 2];
        fn[3] = fstar[rC2 + colmid + 3];
        fn[4] = fstar[rB2 + colR   + 4];
        fn[5] = fstar[rA  + colL   + 5];
        fn[6] = fstar[rC2 + colL   + 6];
        fn[7] = fstar[rC2 + colR   + 7];
        fn[8] = fstar[rA  + colR   + 8];
        if (mk[s]) {
            const int ob = rB2 + colmid;          // own cell, opp reflection
            fn[0] = fstar[ob + 0]; fn[1] = fstar[ob + 3]; fn[2] = fstar[ob + 4];
            fn[3] = fstar[ob + 1]; fn[4] = fstar[ob + 2]; fn[5] = fstar[ob + 7];
            fn[6] = fstar[ob + 8]; fn[7] = fstar[ob + 5]; fn[8] = fstar[ob + 6];
        }
        __syncthreads();                          // (3) all fstar reads done
                                                  //     -> next A may overwrite

        // ---- macro + wave-local stage + dense nt stores (overlaps next A) ----
        const float rhon = fn[0] + fn[1] + fn[2] + fn[3] + fn[4]
                         + fn[5] + fn[6] + fn[7] + fn[8];
        const float irho = __builtin_amdgcn_rcpf(rhon);
        const float uxn = (fn[1] - fn[3] + fn[5] - fn[6] - fn[7] + fn[8]) * irho;
        const float uyn = (fn[2] - fn[4] + fn[5] + fn[6] - fn[7] - fn[8]) * irho;

        #pragma unroll
        for (int i = 0; i < 9; ++i) stg[sbase + i] = fn[i];
        stg[sbase + 9]  = rhon;
        stg[sbase + 10] = uxn;
        stg[sbase + 11] = uyn;
        // wave w reads only wave w's staged cells: no barrier, lgkm-ordered
        const int xorow = (xbase + t * TR + w) * 24576;
        #pragma unroll
        for (int it = 0; it < 3; ++it) {
            floatx4 v;
            v.x = stg[lread[it] + 0];
            v.y = stg[lread[it] + 1];
            v.z = stg[lread[it] + 2];
            v.w = stg[lread[it] + 3];
            __builtin_nontemporal_store(v, reinterpret_cast<floatx4*>(out + xorow + ocol[it]));
        }
    }
}

extern "C" void kernel_launch(void* const* d_in, const int* in_sizes, int n_in,
                              void* d_out, int out_size, void* d_ws, size_t ws_size,
                              hipStream_t stream) {
    const float* f    = (const float*)d_in[0];
    const float* rho  = (const float*)d_in[1];
    const float* u    = (const float*)d_in[2];
    const int*   mask = (const int*)d_in[3];
    float* out = (float*)d_out;

    dim3 block(NT, 1, 1);
    dim3 grid(NY / TC, NX / (TR * TILES), 1);   // 32 x 64
    lbm_step_kernel<<<grid, block, 0, stream>>>(f, rho, u, mask, out);
}